// Round 12
// baseline (418.220 us; speedup 1.0000x reference)
//
#include <hip/hip_runtime.h>
#include <hip/hip_bf16.h>

#define NND 50000
#define NE 800000
#define NM 2
#define INF 256
#define NH 4
#define HDIM 256
#define SHID 128
#define SLOPE 0.2f
#define NB 196          // ceil(NND/256) scan blocks
#define NREP 8          // histogram replicas

typedef unsigned short u16;
typedef __attribute__((ext_vector_type(8))) short bf16x8;
typedef __attribute__((ext_vector_type(4))) float f32x4;

__device__ __forceinline__ float us2f(u16 u) {
  union { unsigned int i; float f; } v; v.i = ((unsigned int)u) << 16; return v.f;
}
__device__ __forceinline__ u16 f2us(float f) {
  union { float f; unsigned int i; } v; v.f = f;
  unsigned int r = v.i + 0x7FFFu + ((v.i >> 16) & 1u);
  return (u16)(r >> 16);
}

#define GLDS(g, l) __builtin_amdgcn_global_load_lds( \
    (const __attribute__((address_space(1))) unsigned int*)(g), \
    (__attribute__((address_space(3))) unsigned int*)(l), 16, 0, 0)

// ---------------- fused prep: h cvt + W/w1 transpose + edge histogram ------
// Blocks 0..6249: h convert. 6250..6281: Wt. 6282..6289: w1t.
// 6290..12539: dst histogram (atomic-latency waves overlap the convert work).
__global__ __launch_bounds__(256) void kprep(
    const float* __restrict__ h, u16* __restrict__ hb,
    const float* __restrict__ W, u16* __restrict__ Wt,
    const float* __restrict__ w1, u16* __restrict__ w1t,
    const int* __restrict__ dst_all, int* __restrict__ hrep)
{
  __shared__ u16 tile[64][65];
  const int t = threadIdx.x;
  const int bid = blockIdx.x;
  if (bid < 6250) {                       // h f32 -> bf16
    const size_t i = ((size_t)bid * 256 + t) * 8;
    float4 a = *(const float4*)(h + i);
    float4 b = *(const float4*)(h + i + 4);
    bf16x8 r;
    r[0] = f2us(a.x); r[1] = f2us(a.y); r[2] = f2us(a.z); r[3] = f2us(a.w);
    r[4] = f2us(b.x); r[5] = f2us(b.y); r[6] = f2us(b.z); r[7] = f2us(b.w);
    *(bf16x8*)(hb + i) = r;
  } else if (bid < 6250 + 32) {           // Wt[m][n][k] = W[m][k][n]
    const int b = bid - 6250;
    const int k0 = (b & 3) * 64, n0 = ((b >> 2) & 3) * 64;
    const float* Wm = W + (size_t)(b >> 4) * 65536;
    u16* Wtm = Wt + (size_t)(b >> 4) * 65536;
    const int lr = t >> 2, c0 = (t & 3) * 16;
#pragma unroll
    for (int i = 0; i < 16; ++i)
      tile[lr][c0 + i] = f2us(Wm[(size_t)(k0 + lr) * 256 + n0 + c0 + i]);
    __syncthreads();
#pragma unroll
    for (int i = 0; i < 16; ++i)
      Wtm[(size_t)(n0 + lr) * 256 + k0 + c0 + i] = tile[c0 + i][lr];
  } else if (bid < 6290) {                // w1t[j][k] = w1[k][j]
    const int b = bid - 6282;
    const int k0 = (b & 3) * 64, j0 = (b >> 2) * 64;
    const int lr = t >> 2, c0 = (t & 3) * 16;
#pragma unroll
    for (int i = 0; i < 16; ++i)
      tile[lr][c0 + i] = f2us(w1[(size_t)(k0 + lr) * SHID + j0 + c0 + i]);
    __syncthreads();
#pragma unroll
    for (int i = 0; i < 16; ++i)
      w1t[(size_t)(j0 + lr) * 256 + k0 + c0 + i] = tile[c0 + i][lr];
  } else {                                // histogram over 2*NE edges
    const int e = (bid - 6290) * 256 + t; // exactly covers [0, 2*NE)
    const int p = (e >= NE) ? 1 : 0;
    const int rep = bid & (NREP - 1);
    atomicAdd(hrep + ((size_t)p * NREP + rep) * (NND + 1) + dst_all[e] + 1, 1);
  }
}

// sum replicas + block-local inclusive scan; grid = 2*NB
__global__ __launch_bounds__(256) void ks1(const int* __restrict__ hrep,
                                           int* __restrict__ rowptr,
                                           int* __restrict__ bsum) {
  __shared__ int wsums[4];
  const int t = threadIdx.x;
  const int p = blockIdx.x / NB, lb = blockIdx.x % NB;
  int* rp = rowptr + (size_t)p * (NND + 1);
  const int i = lb * 256 + t + 1;
  int v = 0;
  if (i <= NND) {
    const int* hp = hrep + (size_t)p * NREP * (NND + 1);
#pragma unroll
    for (int r = 0; r < NREP; ++r) v += hp[(size_t)r * (NND + 1) + i];
  }
  const int lane = t & 63, wid = t >> 6;
#pragma unroll
  for (int o = 1; o < 64; o <<= 1) {
    int u = __shfl_up(v, o, 64);
    if (lane >= o) v += u;
  }
  if (lane == 63) wsums[wid] = v;
  __syncthreads();
  if (t == 0) {
    int s = 0;
#pragma unroll
    for (int w = 0; w < 4; ++w) { int x = wsums[w]; wsums[w] = s; s += x; }
    bsum[blockIdx.x] = s;
  }
  __syncthreads();
  v += wsums[wid];
  if (i <= NND) rp[i] = v;
}

// add block-prefix + materialize single cursor per path
__global__ __launch_bounds__(256) void ks3(int* __restrict__ rowptr,
                                           const int* __restrict__ bsum,
                                           int* __restrict__ cursor) {
  __shared__ int redp[4];
  __shared__ int off_s;
  const int t = threadIdx.x;
  const int p = blockIdx.x / NB, lb = blockIdx.x % NB;
  int* rp = rowptr + (size_t)p * (NND + 1);
  int* cp = cursor + (size_t)p * NND;
  int partial = (t < lb) ? bsum[p * NB + t] : 0;
  const int lane = t & 63, wid = t >> 6;
#pragma unroll
  for (int o = 32; o; o >>= 1) partial += __shfl_xor(partial, o, 64);
  if (lane == 0) redp[wid] = partial;
  __syncthreads();
  if (t == 0) off_s = redp[0] + redp[1] + redp[2] + redp[3];
  __syncthreads();
  const int off = off_s;
  const int i = lb * 256 + t + 1;
  if (i <= NND) {
    int v = rp[i] + off;
    rp[i] = v;
    if (i < NND) cp[i] = v;
    if (i == 1) { cp[0] = 0; rp[0] = 0; }
  }
}

// scatter + per-edge attention exp for all 4 heads (CSR order)
__global__ __launch_bounds__(256) void kc_scatter(
    const int* __restrict__ src, const int* __restrict__ dst,
    int* __restrict__ cursor, int* __restrict__ col,
    const float* __restrict__ el, const float* __restrict__ er,
    float* __restrict__ exps)
{
  int e = blockIdx.x * 256 + threadIdx.x;
  if (e >= NE) return;
  int s = src[e], d = dst[e];
  int pos = atomicAdd(cursor + d, 1);
  col[pos] = s;
  float4 a = *(const float4*)(el + s * 4);
  float4 b = *(const float4*)(er + d * 4);
  float4 r;
  float x;
  x = a.x + b.x; x = x > 0.f ? x : SLOPE * x; r.x = __expf(x);
  x = a.y + b.y; x = x > 0.f ? x : SLOPE * x; r.y = __expf(x);
  x = a.z + b.z; x = x > 0.f ? x : SLOPE * x; r.z = __expf(x);
  x = a.w + b.w; x = x > 0.f ? x : SLOPE * x; r.w = __expf(x);
  *(float4*)(exps + (size_t)pos * 4) = r;
}

// ---------------- K1: feat = h @ W[m] via MFMA, BK=64, swizzled LDS --------
// LDS [128][64] bf16 rows=128B: XOR-swizzle group g -> g^(row&7) (both sides).
__global__ __launch_bounds__(256) void k1_mfma(
    const u16* __restrict__ hb, const u16* __restrict__ Wt,
    u16* __restrict__ feat)
{
  __shared__ u16 As[128 * 64];
  __shared__ u16 Bs[128 * 64];
  const int t = threadIdx.x;
  const int lane = t & 63;
  const int w = t >> 6;
  const int wr = w >> 1, wc = w & 1;
  const int row0 = blockIdx.x * 128;
  const int col0 = blockIdx.y * 128;

  const int srow = t >> 3;              // 0..31
  const int sg   = t & 7;               // phys 8-elem group slot
  const int sgl  = (sg ^ (srow & 7)) * 8;  // swizzled source col offset

  int ra[4], cb[4];
#pragma unroll
  for (int q = 0; q < 4; ++q) {
    int r = row0 + q * 32 + srow; if (r >= NND) r = NND - 1;
    ra[q] = r;
    cb[q] = col0 + q * 32 + srow;
  }

  f32x4 acc[4][4];
#pragma unroll
  for (int i = 0; i < 4; ++i)
#pragma unroll
    for (int j = 0; j < 4; ++j) acc[i][j] = (f32x4){0.f, 0.f, 0.f, 0.f};

  for (int ks = 0; ks < 4; ++ks) {
    const int kb = ks * 64 + sgl;
    __syncthreads();
#pragma unroll
    for (int q = 0; q < 4; ++q) {
      GLDS(hb + (size_t)ra[q] * INF + kb, As + q * 2048 + w * 512);
      GLDS(Wt + (size_t)cb[q] * 256 + kb, Bs + q * 2048 + w * 512);
    }
    __syncthreads();
#pragma unroll
    for (int kk = 0; kk < 2; ++kk) {
      bf16x8 af[4], bfr[4];
#pragma unroll
      for (int mi = 0; mi < 4; ++mi) {
        const int R = wr * 64 + mi * 16 + (lane & 15);
        const int g = kk * 4 + (lane >> 4);
        af[mi] = *(const bf16x8*)(As + R * 64 + (g ^ (R & 7)) * 8);
      }
#pragma unroll
      for (int ni = 0; ni < 4; ++ni) {
        const int R = wc * 64 + ni * 16 + (lane & 15);
        const int g = kk * 4 + (lane >> 4);
        bfr[ni] = *(const bf16x8*)(Bs + R * 64 + (g ^ (R & 7)) * 8);
      }
#pragma unroll
      for (int mi = 0; mi < 4; ++mi)
#pragma unroll
        for (int ni = 0; ni < 4; ++ni)
          acc[mi][ni] = __builtin_amdgcn_mfma_f32_16x16x32_bf16(af[mi], bfr[ni], acc[mi][ni], 0, 0, 0);
    }
  }
#pragma unroll
  for (int mi = 0; mi < 4; ++mi) {
    const int r_base = row0 + wr * 64 + mi * 16 + (lane >> 4) * 4;
#pragma unroll
    for (int i = 0; i < 4; ++i) {
      const int r = r_base + i;
      if (r < NND) {
#pragma unroll
        for (int ni = 0; ni < 4; ++ni) {
          const int c = col0 + wc * 64 + ni * 16 + (lane & 15);
          feat[(size_t)r * HDIM + c] = f2us(acc[mi][ni][i]);
        }
      }
    }
  }
}

// ---------------- K1b: el/er from feat -------------------------------------
__global__ __launch_bounds__(256) void k1b_elr(
    const u16* __restrict__ feat,
    const float* __restrict__ al, const float* __restrict__ ar,
    float* __restrict__ el, float* __restrict__ er)
{
  const int n = blockIdx.x * 4 + (threadIdx.x >> 6);
  const int lane = threadIdx.x & 63;
  ushort4 f4 = *(const ushort4*)(feat + (size_t)n * HDIM + lane * 4);
  float4 a4 = *(const float4*)(al + lane * 4);
  float4 r4 = *(const float4*)(ar + lane * 4);
  float fl = us2f(f4.x) * a4.x + us2f(f4.y) * a4.y
           + us2f(f4.z) * a4.z + us2f(f4.w) * a4.w;
  float fr = us2f(f4.x) * r4.x + us2f(f4.y) * r4.y
           + us2f(f4.z) * r4.z + us2f(f4.w) * r4.w;
#pragma unroll
  for (int o = 1; o < 16; o <<= 1) {
    fl += __shfl_xor(fl, o, 64);
    fr += __shfl_xor(fr, o, 64);
  }
  if ((lane & 15) == 0) {
    el[n * 4 + (lane >> 4)] = fl;
    er[n * 4 + (lane >> 4)] = fr;
  }
}

// ---------------- K3: CSR gather (round-7 form, unchanged) -----------------
template<int OBF>
__global__ __launch_bounds__(256) void k3_gather(
    const int* __restrict__ rowptr, const int* __restrict__ col,
    const float* __restrict__ exps,
    const u16* __restrict__ feat, void* __restrict__ z)
{
  const int d = blockIdx.x * 4 + (threadIdx.x >> 6);
  if (d >= NND) return;
  const int lane = threadIdx.x & 63;
  const int h = lane >> 4;
  const int sub = lane & 15;
  const int beg = rowptr[d], end = rowptr[d + 1];

  float den = 0.f;
  for (int j = beg + sub; j < end; j += 16)
    den += exps[(size_t)j * 4 + h];
#pragma unroll
  for (int o = 1; o < 16; o <<= 1) den += __shfl_xor(den, o, 64);
  const float inv = 1.f / fmaxf(den, 1e-9f);

  float a0 = 0.f, a1 = 0.f, a2 = 0.f, a3 = 0.f;
  int j = beg;
  for (; j + 3 < end; j += 4) {
    int s0 = col[j], s1 = col[j + 1], s2 = col[j + 2], s3 = col[j + 3];
    float p0 = exps[(size_t)j * 4 + h] * inv;
    float p1 = exps[(size_t)(j + 1) * 4 + h] * inv;
    float p2 = exps[(size_t)(j + 2) * 4 + h] * inv;
    float p3 = exps[(size_t)(j + 3) * 4 + h] * inv;
    const ushort4 f0 = *(const ushort4*)(feat + (size_t)s0 * HDIM + lane * 4);
    const ushort4 f1 = *(const ushort4*)(feat + (size_t)s1 * HDIM + lane * 4);
    const ushort4 f2 = *(const ushort4*)(feat + (size_t)s2 * HDIM + lane * 4);
    const ushort4 f3 = *(const ushort4*)(feat + (size_t)s3 * HDIM + lane * 4);
    a0 = fmaf(p0, us2f(f0.x), a0); a1 = fmaf(p0, us2f(f0.y), a1);
    a2 = fmaf(p0, us2f(f0.z), a2); a3 = fmaf(p0, us2f(f0.w), a3);
    a0 = fmaf(p1, us2f(f1.x), a0); a1 = fmaf(p1, us2f(f1.y), a1);
    a2 = fmaf(p1, us2f(f1.z), a2); a3 = fmaf(p1, us2f(f1.w), a3);
    a0 = fmaf(p2, us2f(f2.x), a0); a1 = fmaf(p2, us2f(f2.y), a1);
    a2 = fmaf(p2, us2f(f2.z), a2); a3 = fmaf(p2, us2f(f2.w), a3);
    a0 = fmaf(p3, us2f(f3.x), a0); a1 = fmaf(p3, us2f(f3.y), a1);
    a2 = fmaf(p3, us2f(f3.z), a2); a3 = fmaf(p3, us2f(f3.w), a3);
  }
  for (; j < end; ++j) {
    int s = col[j];
    float p = exps[(size_t)j * 4 + h] * inv;
    const ushort4 f4 = *(const ushort4*)(feat + (size_t)s * HDIM + lane * 4);
    a0 = fmaf(p, us2f(f4.x), a0); a1 = fmaf(p, us2f(f4.y), a1);
    a2 = fmaf(p, us2f(f4.z), a2); a3 = fmaf(p, us2f(f4.w), a3);
  }
  a0 = a0 > 0.f ? a0 : expf(a0) - 1.f;
  a1 = a1 > 0.f ? a1 : expf(a1) - 1.f;
  a2 = a2 > 0.f ? a2 : expf(a2) - 1.f;
  a3 = a3 > 0.f ? a3 : expf(a3) - 1.f;
  const size_t idx = (size_t)d * HDIM + lane * 4;
  if (OBF) {
    ushort4 r; r.x = f2us(a0); r.y = f2us(a1); r.z = f2us(a2); r.w = f2us(a3);
    *(ushort4*)((u16*)z + idx) = r;
  } else {
    float4 r; r.x = a0; r.y = a1; r.z = a2; r.w = a3;
    *(float4*)((float*)z + idx) = r;
  }
}

// ---------------- K4: wsum[m] += sum tanh(z@w1+b1)*w2, BK=64, swizzled -----
template<int ZBF>
__global__ __launch_bounds__(256) void k4_mfma(
    const void* __restrict__ zsrc, const u16* __restrict__ w1t,
    const float* __restrict__ b1, const float* __restrict__ w2,
    float* __restrict__ wsum, int midx)
{
  __shared__ u16 As[128 * 64];
  __shared__ u16 Bs[128 * 64];
  __shared__ float red[4];
  const int t = threadIdx.x;
  const int lane = t & 63;
  const int w = t >> 6;
  const int wr = w >> 1, wc = w & 1;
  const int row0 = blockIdx.x * 128;
  const int srow = t >> 3;
  const int sg   = t & 7;
  const int sgl  = (sg ^ (srow & 7)) * 8;

  int ra[4], cb[4];
#pragma unroll
  for (int q = 0; q < 4; ++q) {
    int r = row0 + q * 32 + srow; if (r >= NND) r = NND - 1;
    ra[q] = r;
    cb[q] = q * 32 + srow;              // w1t rows 0..127
  }

  f32x4 acc[4][4];
#pragma unroll
  for (int i = 0; i < 4; ++i)
#pragma unroll
    for (int j = 0; j < 4; ++j) acc[i][j] = (f32x4){0.f, 0.f, 0.f, 0.f};

  for (int ks = 0; ks < 4; ++ks) {
    const int kb = ks * 64 + sgl;
    __syncthreads();
    if (ZBF) {
#pragma unroll
      for (int q = 0; q < 4; ++q)
        GLDS((const u16*)zsrc + (size_t)ra[q] * HDIM + kb, As + q * 2048 + w * 512);
    } else {
      const float* zf = (const float*)zsrc;
#pragma unroll
      for (int q = 0; q < 4; ++q) {
        float4 a = *(const float4*)(zf + (size_t)ra[q] * HDIM + kb);
        float4 b = *(const float4*)(zf + (size_t)ra[q] * HDIM + kb + 4);
        bf16x8 r;
        r[0] = f2us(a.x); r[1] = f2us(a.y); r[2] = f2us(a.z); r[3] = f2us(a.w);
        r[4] = f2us(b.x); r[5] = f2us(b.y); r[6] = f2us(b.z); r[7] = f2us(b.w);
        *(bf16x8*)(As + (q * 32 + srow) * 64 + (sg ^ (srow & 7)) * 8) = r;
      }
    }
#pragma unroll
    for (int q = 0; q < 4; ++q)
      GLDS(w1t + (size_t)cb[q] * 256 + kb, Bs + q * 2048 + w * 512);
    __syncthreads();
#pragma unroll
    for (int kk = 0; kk < 2; ++kk) {
      bf16x8 af[4], bfr[4];
#pragma unroll
      for (int mi = 0; mi < 4; ++mi) {
        const int R = wr * 64 + mi * 16 + (lane & 15);
        const int g = kk * 4 + (lane >> 4);
        af[mi] = *(const bf16x8*)(As + R * 64 + (g ^ (R & 7)) * 8);
      }
#pragma unroll
      for (int ni = 0; ni < 4; ++ni) {
        const int R = wc * 64 + ni * 16 + (lane & 15);
        const int g = kk * 4 + (lane >> 4);
        bfr[ni] = *(const bf16x8*)(Bs + R * 64 + (g ^ (R & 7)) * 8);
      }
#pragma unroll
      for (int mi = 0; mi < 4; ++mi)
#pragma unroll
        for (int ni = 0; ni < 4; ++ni)
          acc[mi][ni] = __builtin_amdgcn_mfma_f32_16x16x32_bf16(af[mi], bfr[ni], acc[mi][ni], 0, 0, 0);
    }
  }
  float sum = 0.f;
#pragma unroll
  for (int ni = 0; ni < 4; ++ni) {
    const int c = wc * 64 + ni * 16 + (lane & 15);
    const float b1c = b1[c], w2c = w2[c];
#pragma unroll
    for (int mi = 0; mi < 4; ++mi) {
      const int r_base = row0 + wr * 64 + mi * 16 + (lane >> 4) * 4;
#pragma unroll
      for (int i = 0; i < 4; ++i) {
        if (r_base + i < NND)
          sum += tanhf(acc[mi][ni][i] + b1c) * w2c;
      }
    }
  }
#pragma unroll
  for (int o = 32; o; o >>= 1) sum += __shfl_xor(sum, o, 64);
  if (lane == 0) red[w] = sum;
  __syncthreads();
  if (t == 0) unsafeAtomicAdd(wsum + midx, red[0] + red[1] + red[2] + red[3]);
}

// ---------------- K5: beta=softmax(wsum/N); out = b0*z0 + b1*z1 ------------
__global__ __launch_bounds__(256) void k5_out(
    float* __restrict__ out, const u16* __restrict__ z1,
    const float* __restrict__ wsum)
{
  const int i = blockIdx.x * 256 + threadIdx.x;
  float w0 = wsum[0] * (1.0f / NND);
  float w1v = wsum[1] * (1.0f / NND);
  float mx = fmaxf(w0, w1v);
  float e0 = expf(w0 - mx), e1 = expf(w1v - mx);
  float inv = 1.f / (e0 + e1);
  float b0 = e0 * inv, b1 = e1 * inv;
  float4 a = ((const float4*)out)[i];
  ushort4 zb = ((const ushort4*)z1)[i];
  float4 r;
  r.x = b0 * a.x + b1 * us2f(zb.x);
  r.y = b0 * a.y + b1 * us2f(zb.y);
  r.z = b0 * a.z + b1 * us2f(zb.z);
  r.w = b0 * a.w + b1 * us2f(zb.w);
  ((float4*)out)[i] = r;
}

extern "C" void kernel_launch(void* const* d_in, const int* in_sizes, int n_in,
                              void* d_out, int out_size, void* d_ws, size_t ws_size,
                              hipStream_t stream)
{
  const float* h  = (const float*)d_in[0];
  const int* src  = (const int*)d_in[1];
  const int* dst  = (const int*)d_in[2];
  const float* W  = (const float*)d_in[3];
  const float* al = (const float*)d_in[4];
  const float* ar = (const float*)d_in[5];
  const float* w1 = (const float*)d_in[6];
  const float* b1 = (const float*)d_in[7];
  const float* w2 = (const float*)d_in[8];

  // workspace layout (bytes)
  char* wsb = (char*)d_ws;
  u16*   feat   = (u16*)(wsb);                 // 25,600,000
  u16*   hz     = (u16*)(wsb + 25600000);      // 25,600,000  (bf16 h; z1 aliases)
  float* exps   = (float*)(wsb + 51200000);    // 12,800,000
  int*   col    = (int*)(wsb + 64000000);      //  3,200,000
  u16*   Wt     = (u16*)(wsb + 67200000);      //    262,144
  u16*   w1t    = (u16*)(wsb + 67462144);      //     65,536
  float* el     = (float*)(wsb + 67527680);    //    800,000
  float* er     = (float*)(wsb + 68327680);    //    800,000
  int*   rowptr = (int*)(wsb + 69127680);      //    400,008 (2 paths)
  int*   cursor = (int*)(wsb + 69527688);      //    400,000 (2 paths)
  float* wsum   = (float*)(wsb + 69927688);    //          8
  int*   bsum   = (int*)(wsb + 69927696);      //      1,568 (2*NB)
  int*   hrep   = (int*)(wsb + 69929264);      //  3,200,064 (2*NREP*(NND+1))
  const size_t NEED = 73129328;
  if (ws_size < NEED) {
    hipMemsetAsync(d_out, 0x7F, (size_t)out_size * 4, stream);
    return;
  }
  u16* z1 = hz;        // alias: hz dead after k1_mfma(m=1), z1 written by k3(m=1)
  float* outp = (float*)d_out;

  // phase A: fused prep+hist, then scan
  hipMemsetAsync(wsum, 0, 2 * sizeof(float), stream);
  hipMemsetAsync(hrep, 0, (size_t)2 * NREP * (NND + 1) * sizeof(int), stream);
  kprep<<<12540, 256, 0, stream>>>(h, hz, W, Wt, w1, w1t, dst, hrep);
  ks1<<<2 * NB, 256, 0, stream>>>(hrep, rowptr, bsum);
  ks3<<<2 * NB, 256, 0, stream>>>(rowptr, bsum, cursor);

  // phase B: per meta-path
  for (int m = 0; m < NM; ++m) {
    const int* src_m = src + (size_t)m * NE;
    const int* dst_m = dst + (size_t)m * NE;
    int* rowptr_m = rowptr + (size_t)m * (NND + 1);
    int* cursor_m = cursor + (size_t)m * NND;
    k1_mfma<<<dim3(391, 2), 256, 0, stream>>>(hz, Wt + (size_t)m * 65536, feat);
    k1b_elr<<<12500, 256, 0, stream>>>(feat, al + (size_t)m * HDIM, ar + (size_t)m * HDIM, el, er);
    kc_scatter<<<NE / 256, 256, 0, stream>>>(src_m, dst_m, cursor_m, col, el, er, exps);
    if (m == 0) {
      k3_gather<0><<<12500, 256, 0, stream>>>(rowptr_m, col, exps, feat, d_out);
      k4_mfma<0><<<391, 256, 0, stream>>>(d_out, w1t, b1, w2, wsum, 0);
    } else {
      k3_gather<1><<<12500, 256, 0, stream>>>(rowptr_m, col, exps, feat, z1);
      k4_mfma<1><<<391, 256, 0, stream>>>(z1, w1t, b1, w2, wsum, 1);
    }
  }
  k5_out<<<(NND * HDIM / 4) / 256, 256, 0, stream>>>(outp, z1, wsum);
}

// Round 13
// 414.378 us; speedup vs baseline: 1.0093x; 1.0093x over previous
//
#include <hip/hip_runtime.h>
#include <hip/hip_bf16.h>

#define NND 50000
#define NE 800000
#define NM 2
#define INF 256
#define NH 4
#define HDIM 256
#define SHID 128
#define SLOPE 0.2f
#define NB 196          // ceil(NND/256) scan blocks
#define NREP 8          // histogram replicas

typedef unsigned short u16;
typedef __attribute__((ext_vector_type(8))) short bf16x8;
typedef __attribute__((ext_vector_type(4))) float f32x4;

__device__ __forceinline__ float us2f(u16 u) {
  union { unsigned int i; float f; } v; v.i = ((unsigned int)u) << 16; return v.f;
}
__device__ __forceinline__ u16 f2us(float f) {
  union { float f; unsigned int i; } v; v.f = f;
  unsigned int r = v.i + 0x7FFFu + ((v.i >> 16) & 1u);
  return (u16)(r >> 16);
}

#define GLDS(g, l) __builtin_amdgcn_global_load_lds( \
    (const __attribute__((address_space(1))) unsigned int*)(g), \
    (__attribute__((address_space(3))) unsigned int*)(l), 16, 0, 0)

// ---------------- fused prep: h cvt + W transpose + w1 transpose -----------
__global__ __launch_bounds__(256) void kprep(
    const float* __restrict__ h, u16* __restrict__ hb,
    const float* __restrict__ W, u16* __restrict__ Wt,
    const float* __restrict__ w1, u16* __restrict__ w1t)
{
  __shared__ u16 tile[64][65];
  const int t = threadIdx.x;
  const int bid = blockIdx.x;
  if (bid < 6250) {                       // h f32 -> bf16
    const size_t i = ((size_t)bid * 256 + t) * 8;
    float4 a = *(const float4*)(h + i);
    float4 b = *(const float4*)(h + i + 4);
    bf16x8 r;
    r[0] = f2us(a.x); r[1] = f2us(a.y); r[2] = f2us(a.z); r[3] = f2us(a.w);
    r[4] = f2us(b.x); r[5] = f2us(b.y); r[6] = f2us(b.z); r[7] = f2us(b.w);
    *(bf16x8*)(hb + i) = r;
  } else if (bid < 6250 + 32) {           // Wt[m][n][k] = W[m][k][n]
    const int b = bid - 6250;
    const int k0 = (b & 3) * 64, n0 = ((b >> 2) & 3) * 64;
    const float* Wm = W + (size_t)(b >> 4) * 65536;
    u16* Wtm = Wt + (size_t)(b >> 4) * 65536;
    const int lr = t >> 2, c0 = (t & 3) * 16;
#pragma unroll
    for (int i = 0; i < 16; ++i)
      tile[lr][c0 + i] = f2us(Wm[(size_t)(k0 + lr) * 256 + n0 + c0 + i]);
    __syncthreads();
#pragma unroll
    for (int i = 0; i < 16; ++i)
      Wtm[(size_t)(n0 + lr) * 256 + k0 + c0 + i] = tile[c0 + i][lr];
  } else {                                // w1t[j][k] = w1[k][j]
    const int b = bid - 6282;
    const int k0 = (b & 3) * 64, j0 = (b >> 2) * 64;
    const int lr = t >> 2, c0 = (t & 3) * 16;
#pragma unroll
    for (int i = 0; i < 16; ++i)
      tile[lr][c0 + i] = f2us(w1[(size_t)(k0 + lr) * SHID + j0 + c0 + i]);
    __syncthreads();
#pragma unroll
    for (int i = 0; i < 16; ++i)
      w1t[(size_t)(j0 + lr) * 256 + k0 + c0 + i] = tile[c0 + i][lr];
  }
}

// ---------------- CSR build (both meta-paths, replicated histogram) --------
__global__ __launch_bounds__(256) void kc_hist_both(const int* __restrict__ dst_all,
                                                    int* __restrict__ hrep) {
  int e = blockIdx.x * 256 + threadIdx.x;      // e < 2*NE
  int p = (e >= NE) ? 1 : 0;
  int rep = blockIdx.x & (NREP - 1);
  atomicAdd(hrep + ((size_t)p * NREP + rep) * (NND + 1) + dst_all[e] + 1, 1);
}

// sum replicas + block-local inclusive scan; grid = 2*NB
__global__ __launch_bounds__(256) void ks1(const int* __restrict__ hrep,
                                           int* __restrict__ rowptr,
                                           int* __restrict__ bsum) {
  __shared__ int wsums[4];
  const int t = threadIdx.x;
  const int p = blockIdx.x / NB, lb = blockIdx.x % NB;
  int* rp = rowptr + (size_t)p * (NND + 1);
  const int i = lb * 256 + t + 1;
  int v = 0;
  if (i <= NND) {
    const int* hp = hrep + (size_t)p * NREP * (NND + 1);
#pragma unroll
    for (int r = 0; r < NREP; ++r) v += hp[(size_t)r * (NND + 1) + i];
  }
  const int lane = t & 63, wid = t >> 6;
#pragma unroll
  for (int o = 1; o < 64; o <<= 1) {
    int u = __shfl_up(v, o, 64);
    if (lane >= o) v += u;
  }
  if (lane == 63) wsums[wid] = v;
  __syncthreads();
  if (t == 0) {
    int s = 0;
#pragma unroll
    for (int w = 0; w < 4; ++w) { int x = wsums[w]; wsums[w] = s; s += x; }
    bsum[blockIdx.x] = s;
  }
  __syncthreads();
  v += wsums[wid];
  if (i <= NND) rp[i] = v;
}

// add block-prefix + materialize single cursor per path
__global__ __launch_bounds__(256) void ks3(int* __restrict__ rowptr,
                                           const int* __restrict__ bsum,
                                           int* __restrict__ cursor) {
  __shared__ int redp[4];
  __shared__ int off_s;
  const int t = threadIdx.x;
  const int p = blockIdx.x / NB, lb = blockIdx.x % NB;
  int* rp = rowptr + (size_t)p * (NND + 1);
  int* cp = cursor + (size_t)p * NND;
  int partial = (t < lb) ? bsum[p * NB + t] : 0;
  const int lane = t & 63, wid = t >> 6;
#pragma unroll
  for (int o = 32; o; o >>= 1) partial += __shfl_xor(partial, o, 64);
  if (lane == 0) redp[wid] = partial;
  __syncthreads();
  if (t == 0) off_s = redp[0] + redp[1] + redp[2] + redp[3];
  __syncthreads();
  const int off = off_s;
  const int i = lb * 256 + t + 1;
  if (i <= NND) {
    int v = rp[i] + off;
    rp[i] = v;
    if (i < NND) cp[i] = v;
    if (i == 1) { cp[0] = 0; rp[0] = 0; }
  }
}

// scatter + per-edge attention exp for all 4 heads (CSR order)
__global__ __launch_bounds__(256) void kc_scatter(
    const int* __restrict__ src, const int* __restrict__ dst,
    int* __restrict__ cursor, int* __restrict__ col,
    const float* __restrict__ el, const float* __restrict__ er,
    float* __restrict__ exps)
{
  int e = blockIdx.x * 256 + threadIdx.x;
  if (e >= NE) return;
  int s = src[e], d = dst[e];
  int pos = atomicAdd(cursor + d, 1);
  col[pos] = s;
  float4 a = *(const float4*)(el + s * 4);
  float4 b = *(const float4*)(er + d * 4);
  float4 r;
  float x;
  x = a.x + b.x; x = x > 0.f ? x : SLOPE * x; r.x = __expf(x);
  x = a.y + b.y; x = x > 0.f ? x : SLOPE * x; r.y = __expf(x);
  x = a.z + b.z; x = x > 0.f ? x : SLOPE * x; r.z = __expf(x);
  x = a.w + b.w; x = x > 0.f ? x : SLOPE * x; r.w = __expf(x);
  *(float4*)(exps + (size_t)pos * 4) = r;
}

// ---------------- K1: feat = h @ W[m] via MFMA, BK=64, fused el/er ---------
// 128x128 tile; wave (wr,wc)'s 64 cols = exactly head (col0/64 + wc), so
// el/er[r, head] is a complete per-wave sum: 16-lane shfl reduce, plain store.
__global__ __launch_bounds__(256) void k1_mfma(
    const u16* __restrict__ hb, const u16* __restrict__ Wt,
    const float* __restrict__ al, const float* __restrict__ ar,
    u16* __restrict__ feat, float* __restrict__ el, float* __restrict__ er)
{
  __shared__ u16 As[128 * 64];
  __shared__ u16 Bs[128 * 64];
  const int t = threadIdx.x;
  const int lane = t & 63;
  const int w = t >> 6;
  const int wr = w >> 1, wc = w & 1;
  const int row0 = blockIdx.x * 128;
  const int col0 = blockIdx.y * 128;

  const int srow = t >> 3;              // 0..31
  const int sg   = t & 7;               // phys 8-elem group slot
  const int sgl  = (sg ^ (srow & 7)) * 8;  // swizzled source col offset

  int ra[4], cb[4];
#pragma unroll
  for (int q = 0; q < 4; ++q) {
    int r = row0 + q * 32 + srow; if (r >= NND) r = NND - 1;
    ra[q] = r;
    cb[q] = col0 + q * 32 + srow;
  }

  f32x4 acc[4][4];
#pragma unroll
  for (int i = 0; i < 4; ++i)
#pragma unroll
    for (int j = 0; j < 4; ++j) acc[i][j] = (f32x4){0.f, 0.f, 0.f, 0.f};

  for (int ks = 0; ks < 4; ++ks) {
    const int kb = ks * 64 + sgl;
    __syncthreads();
#pragma unroll
    for (int q = 0; q < 4; ++q) {
      GLDS(hb + (size_t)ra[q] * INF + kb, As + q * 2048 + w * 512);
      GLDS(Wt + (size_t)cb[q] * 256 + kb, Bs + q * 2048 + w * 512);
    }
    __syncthreads();
#pragma unroll
    for (int kk = 0; kk < 2; ++kk) {
      bf16x8 af[4], bfr[4];
#pragma unroll
      for (int mi = 0; mi < 4; ++mi) {
        const int R = wr * 64 + mi * 16 + (lane & 15);
        const int g = kk * 4 + (lane >> 4);
        af[mi] = *(const bf16x8*)(As + R * 64 + (g ^ (R & 7)) * 8);
      }
#pragma unroll
      for (int ni = 0; ni < 4; ++ni) {
        const int R = wc * 64 + ni * 16 + (lane & 15);
        const int g = kk * 4 + (lane >> 4);
        bfr[ni] = *(const bf16x8*)(Bs + R * 64 + (g ^ (R & 7)) * 8);
      }
#pragma unroll
      for (int mi = 0; mi < 4; ++mi)
#pragma unroll
        for (int ni = 0; ni < 4; ++ni)
          acc[mi][ni] = __builtin_amdgcn_mfma_f32_16x16x32_bf16(af[mi], bfr[ni], acc[mi][ni], 0, 0, 0);
    }
  }
  // epilogue: feat store + fused el/er (C layout col=lane&15, row=(lane>>4)*4+i)
  const int head = (col0 >> 6) + wc;     // this wave's head (cols head*64..+64)
  float alc[4], arc[4];
#pragma unroll
  for (int ni = 0; ni < 4; ++ni) {
    const int c = col0 + wc * 64 + ni * 16 + (lane & 15);
    alc[ni] = al[c]; arc[ni] = ar[c];
  }
#pragma unroll
  for (int mi = 0; mi < 4; ++mi) {
#pragma unroll
    for (int i = 0; i < 4; ++i) {
      const int r = row0 + wr * 64 + mi * 16 + (lane >> 4) * 4 + i;
      const bool valid = (r < NND);
      float pel = 0.f, per = 0.f;
#pragma unroll
      for (int ni = 0; ni < 4; ++ni) {
        const float fe = acc[mi][ni][i];
        if (valid)
          feat[(size_t)r * HDIM + col0 + wc * 64 + ni * 16 + (lane & 15)] = f2us(fe);
        pel = fmaf(fe, alc[ni], pel);
        per = fmaf(fe, arc[ni], per);
      }
#pragma unroll
      for (int o = 1; o < 16; o <<= 1) {
        pel += __shfl_xor(pel, o, 64);
        per += __shfl_xor(per, o, 64);
      }
      if (valid && (lane & 15) == 0) {
        el[r * 4 + head] = pel;
        er[r * 4 + head] = per;
      }
    }
  }
}

// ---------------- K3: CSR gather (round-7 form, unchanged) -----------------
template<int OBF>
__global__ __launch_bounds__(256) void k3_gather(
    const int* __restrict__ rowptr, const int* __restrict__ col,
    const float* __restrict__ exps,
    const u16* __restrict__ feat, void* __restrict__ z)
{
  const int d = blockIdx.x * 4 + (threadIdx.x >> 6);
  if (d >= NND) return;
  const int lane = threadIdx.x & 63;
  const int h = lane >> 4;
  const int sub = lane & 15;
  const int beg = rowptr[d], end = rowptr[d + 1];

  float den = 0.f;
  for (int j = beg + sub; j < end; j += 16)
    den += exps[(size_t)j * 4 + h];
#pragma unroll
  for (int o = 1; o < 16; o <<= 1) den += __shfl_xor(den, o, 64);
  const float inv = 1.f / fmaxf(den, 1e-9f);

  float a0 = 0.f, a1 = 0.f, a2 = 0.f, a3 = 0.f;
  int j = beg;
  for (; j + 3 < end; j += 4) {
    int s0 = col[j], s1 = col[j + 1], s2 = col[j + 2], s3 = col[j + 3];
    float p0 = exps[(size_t)j * 4 + h] * inv;
    float p1 = exps[(size_t)(j + 1) * 4 + h] * inv;
    float p2 = exps[(size_t)(j + 2) * 4 + h] * inv;
    float p3 = exps[(size_t)(j + 3) * 4 + h] * inv;
    const ushort4 f0 = *(const ushort4*)(feat + (size_t)s0 * HDIM + lane * 4);
    const ushort4 f1 = *(const ushort4*)(feat + (size_t)s1 * HDIM + lane * 4);
    const ushort4 f2 = *(const ushort4*)(feat + (size_t)s2 * HDIM + lane * 4);
    const ushort4 f3 = *(const ushort4*)(feat + (size_t)s3 * HDIM + lane * 4);
    a0 = fmaf(p0, us2f(f0.x), a0); a1 = fmaf(p0, us2f(f0.y), a1);
    a2 = fmaf(p0, us2f(f0.z), a2); a3 = fmaf(p0, us2f(f0.w), a3);
    a0 = fmaf(p1, us2f(f1.x), a0); a1 = fmaf(p1, us2f(f1.y), a1);
    a2 = fmaf(p1, us2f(f1.z), a2); a3 = fmaf(p1, us2f(f1.w), a3);
    a0 = fmaf(p2, us2f(f2.x), a0); a1 = fmaf(p2, us2f(f2.y), a1);
    a2 = fmaf(p2, us2f(f2.z), a2); a3 = fmaf(p2, us2f(f2.w), a3);
    a0 = fmaf(p3, us2f(f3.x), a0); a1 = fmaf(p3, us2f(f3.y), a1);
    a2 = fmaf(p3, us2f(f3.z), a2); a3 = fmaf(p3, us2f(f3.w), a3);
  }
  for (; j < end; ++j) {
    int s = col[j];
    float p = exps[(size_t)j * 4 + h] * inv;
    const ushort4 f4 = *(const ushort4*)(feat + (size_t)s * HDIM + lane * 4);
    a0 = fmaf(p, us2f(f4.x), a0); a1 = fmaf(p, us2f(f4.y), a1);
    a2 = fmaf(p, us2f(f4.z), a2); a3 = fmaf(p, us2f(f4.w), a3);
  }
  a0 = a0 > 0.f ? a0 : expf(a0) - 1.f;
  a1 = a1 > 0.f ? a1 : expf(a1) - 1.f;
  a2 = a2 > 0.f ? a2 : expf(a2) - 1.f;
  a3 = a3 > 0.f ? a3 : expf(a3) - 1.f;
  const size_t idx = (size_t)d * HDIM + lane * 4;
  if (OBF) {
    ushort4 r; r.x = f2us(a0); r.y = f2us(a1); r.z = f2us(a2); r.w = f2us(a3);
    *(ushort4*)((u16*)z + idx) = r;
  } else {
    float4 r; r.x = a0; r.y = a1; r.z = a2; r.w = a3;
    *(float4*)((float*)z + idx) = r;
  }
}

// ---------------- K4: wsum[m] += sum tanh(z@w1+b1)*w2, BK=64, swizzled -----
template<int ZBF>
__global__ __launch_bounds__(256) void k4_mfma(
    const void* __restrict__ zsrc, const u16* __restrict__ w1t,
    const float* __restrict__ b1, const float* __restrict__ w2,
    float* __restrict__ wsum, int midx)
{
  __shared__ u16 As[128 * 64];
  __shared__ u16 Bs[128 * 64];
  __shared__ float red[4];
  const int t = threadIdx.x;
  const int lane = t & 63;
  const int w = t >> 6;
  const int wr = w >> 1, wc = w & 1;
  const int row0 = blockIdx.x * 128;
  const int srow = t >> 3;
  const int sg   = t & 7;
  const int sgl  = (sg ^ (srow & 7)) * 8;

  int ra[4], cb[4];
#pragma unroll
  for (int q = 0; q < 4; ++q) {
    int r = row0 + q * 32 + srow; if (r >= NND) r = NND - 1;
    ra[q] = r;
    cb[q] = q * 32 + srow;              // w1t rows 0..127
  }

  f32x4 acc[4][4];
#pragma unroll
  for (int i = 0; i < 4; ++i)
#pragma unroll
    for (int j = 0; j < 4; ++j) acc[i][j] = (f32x4){0.f, 0.f, 0.f, 0.f};

  for (int ks = 0; ks < 4; ++ks) {
    const int kb = ks * 64 + sgl;
    __syncthreads();
    if (ZBF) {
#pragma unroll
      for (int q = 0; q < 4; ++q)
        GLDS((const u16*)zsrc + (size_t)ra[q] * HDIM + kb, As + q * 2048 + w * 512);
    } else {
      const float* zf = (const float*)zsrc;
#pragma unroll
      for (int q = 0; q < 4; ++q) {
        float4 a = *(const float4*)(zf + (size_t)ra[q] * HDIM + kb);
        float4 b = *(const float4*)(zf + (size_t)ra[q] * HDIM + kb + 4);
        bf16x8 r;
        r[0] = f2us(a.x); r[1] = f2us(a.y); r[2] = f2us(a.z); r[3] = f2us(a.w);
        r[4] = f2us(b.x); r[5] = f2us(b.y); r[6] = f2us(b.z); r[7] = f2us(b.w);
        *(bf16x8*)(As + (q * 32 + srow) * 64 + (sg ^ (srow & 7)) * 8) = r;
      }
    }
#pragma unroll
    for (int q = 0; q < 4; ++q)
      GLDS(w1t + (size_t)cb[q] * 256 + kb, Bs + q * 2048 + w * 512);
    __syncthreads();
#pragma unroll
    for (int kk = 0; kk < 2; ++kk) {
      bf16x8 af[4], bfr[4];
#pragma unroll
      for (int mi = 0; mi < 4; ++mi) {
        const int R = wr * 64 + mi * 16 + (lane & 15);
        const int g = kk * 4 + (lane >> 4);
        af[mi] = *(const bf16x8*)(As + R * 64 + (g ^ (R & 7)) * 8);
      }
#pragma unroll
      for (int ni = 0; ni < 4; ++ni) {
        const int R = wc * 64 + ni * 16 + (lane & 15);
        const int g = kk * 4 + (lane >> 4);
        bfr[ni] = *(const bf16x8*)(Bs + R * 64 + (g ^ (R & 7)) * 8);
      }
#pragma unroll
      for (int mi = 0; mi < 4; ++mi)
#pragma unroll
        for (int ni = 0; ni < 4; ++ni)
          acc[mi][ni] = __builtin_amdgcn_mfma_f32_16x16x32_bf16(af[mi], bfr[ni], acc[mi][ni], 0, 0, 0);
    }
  }
  float sum = 0.f;
#pragma unroll
  for (int ni = 0; ni < 4; ++ni) {
    const int c = wc * 64 + ni * 16 + (lane & 15);
    const float b1c = b1[c], w2c = w2[c];
#pragma unroll
    for (int mi = 0; mi < 4; ++mi) {
      const int r_base = row0 + wr * 64 + mi * 16 + (lane >> 4) * 4;
#pragma unroll
      for (int i = 0; i < 4; ++i) {
        if (r_base + i < NND)
          sum += tanhf(acc[mi][ni][i] + b1c) * w2c;
      }
    }
  }
#pragma unroll
  for (int o = 32; o; o >>= 1) sum += __shfl_xor(sum, o, 64);
  if (lane == 0) red[w] = sum;
  __syncthreads();
  if (t == 0) unsafeAtomicAdd(wsum + midx, red[0] + red[1] + red[2] + red[3]);
}

// ---------------- K5: beta=softmax(wsum/N); out = b0*z0 + b1*z1 ------------
__global__ __launch_bounds__(256) void k5_out(
    float* __restrict__ out, const u16* __restrict__ z1,
    const float* __restrict__ wsum)
{
  const int i = blockIdx.x * 256 + threadIdx.x;
  float w0 = wsum[0] * (1.0f / NND);
  float w1v = wsum[1] * (1.0f / NND);
  float mx = fmaxf(w0, w1v);
  float e0 = expf(w0 - mx), e1 = expf(w1v - mx);
  float inv = 1.f / (e0 + e1);
  float b0 = e0 * inv, b1 = e1 * inv;
  float4 a = ((const float4*)out)[i];
  ushort4 zb = ((const ushort4*)z1)[i];
  float4 r;
  r.x = b0 * a.x + b1 * us2f(zb.x);
  r.y = b0 * a.y + b1 * us2f(zb.y);
  r.z = b0 * a.z + b1 * us2f(zb.z);
  r.w = b0 * a.w + b1 * us2f(zb.w);
  ((float4*)out)[i] = r;
}

extern "C" void kernel_launch(void* const* d_in, const int* in_sizes, int n_in,
                              void* d_out, int out_size, void* d_ws, size_t ws_size,
                              hipStream_t stream)
{
  const float* h  = (const float*)d_in[0];
  const int* src  = (const int*)d_in[1];
  const int* dst  = (const int*)d_in[2];
  const float* W  = (const float*)d_in[3];
  const float* al = (const float*)d_in[4];
  const float* ar = (const float*)d_in[5];
  const float* w1 = (const float*)d_in[6];
  const float* b1 = (const float*)d_in[7];
  const float* w2 = (const float*)d_in[8];

  // workspace layout (bytes)
  char* wsb = (char*)d_ws;
  u16*   feat   = (u16*)(wsb);                 // 25,600,000
  u16*   hz     = (u16*)(wsb + 25600000);      // 25,600,000  (bf16 h; z1 aliases)
  float* exps   = (float*)(wsb + 51200000);    // 12,800,000
  int*   col    = (int*)(wsb + 64000000);      //  3,200,000
  u16*   Wt     = (u16*)(wsb + 67200000);      //    262,144
  u16*   w1t    = (u16*)(wsb + 67462144);      //     65,536
  float* el     = (float*)(wsb + 67527680);    //    800,000
  float* er     = (float*)(wsb + 68327680);    //    800,000
  int*   rowptr = (int*)(wsb + 69127680);      //    400,008 (2 paths)
  int*   cursor = (int*)(wsb + 69527688);      //    400,000 (2 paths)
  float* wsum   = (float*)(wsb + 69927688);    //          8
  int*   bsum   = (int*)(wsb + 69927696);      //      1,568 (2*NB)
  int*   hrep   = (int*)(wsb + 69929264);      //  3,200,064 (2*NREP*(NND+1))
  const size_t NEED = 73129328;
  if (ws_size < NEED) {
    hipMemsetAsync(d_out, 0x7F, (size_t)out_size * 4, stream);
    return;
  }
  u16* z1 = hz;        // alias: hz dead after k1_mfma(m=1), z1 written by k3(m=1)
  float* outp = (float*)d_out;

  // phase A: prep + full CSR build for both paths
  kprep<<<6290, 256, 0, stream>>>(h, hz, W, Wt, w1, w1t);
  hipMemsetAsync(wsum, 0, 2 * sizeof(float), stream);
  hipMemsetAsync(hrep, 0, (size_t)2 * NREP * (NND + 1) * sizeof(int), stream);
  kc_hist_both<<<2 * NE / 256, 256, 0, stream>>>(dst, hrep);
  ks1<<<2 * NB, 256, 0, stream>>>(hrep, rowptr, bsum);
  ks3<<<2 * NB, 256, 0, stream>>>(rowptr, bsum, cursor);

  // phase B: per meta-path
  for (int m = 0; m < NM; ++m) {
    const int* src_m = src + (size_t)m * NE;
    const int* dst_m = dst + (size_t)m * NE;
    int* rowptr_m = rowptr + (size_t)m * (NND + 1);
    int* cursor_m = cursor + (size_t)m * NND;
    k1_mfma<<<dim3(391, 2), 256, 0, stream>>>(hz, Wt + (size_t)m * 65536,
                                              al + (size_t)m * HDIM, ar + (size_t)m * HDIM,
                                              feat, el, er);
    kc_scatter<<<NE / 256, 256, 0, stream>>>(src_m, dst_m, cursor_m, col, el, er, exps);
    if (m == 0) {
      k3_gather<0><<<12500, 256, 0, stream>>>(rowptr_m, col, exps, feat, d_out);
      k4_mfma<0><<<391, 256, 0, stream>>>(d_out, w1t, b1, w2, wsum, 0);
    } else {
      k3_gather<1><<<12500, 256, 0, stream>>>(rowptr_m, col, exps, feat, z1);
      k4_mfma<1><<<391, 256, 0, stream>>>(z1, w1t, b1, w2, wsum, 1);
    }
  }
  k5_out<<<(NND * HDIM / 4) / 256, 256, 0, stream>>>(outp, z1, wsum);
}

// Round 14
// 397.076 us; speedup vs baseline: 1.0532x; 1.0436x over previous
//
#include <hip/hip_runtime.h>
#include <hip/hip_bf16.h>

#define NND 50000
#define NE 800000
#define NM 2
#define INF 256
#define NH 4
#define HDIM 256
#define SHID 128
#define SLOPE 0.2f
#define NB 196          // ceil(NND/256) scan blocks
#define NREP 16         // histogram replicas

typedef unsigned short u16;
typedef __attribute__((ext_vector_type(8))) short bf16x8;
typedef __attribute__((ext_vector_type(4))) float f32x4;

__device__ __forceinline__ float us2f(u16 u) {
  union { unsigned int i; float f; } v; v.i = ((unsigned int)u) << 16; return v.f;
}
__device__ __forceinline__ u16 f2us(float f) {
  union { float f; unsigned int i; } v; v.f = f;
  unsigned int r = v.i + 0x7FFFu + ((v.i >> 16) & 1u);
  return (u16)(r >> 16);
}

#define GLDS(g, l) __builtin_amdgcn_global_load_lds( \
    (const __attribute__((address_space(1))) unsigned int*)(g), \
    (__attribute__((address_space(3))) unsigned int*)(l), 16, 0, 0)

// ---------------- fused prep: h cvt + W transpose + w1 transpose -----------
__global__ __launch_bounds__(256) void kprep(
    const float* __restrict__ h, u16* __restrict__ hb,
    const float* __restrict__ W, u16* __restrict__ Wt,
    const float* __restrict__ w1, u16* __restrict__ w1t)
{
  __shared__ u16 tile[64][65];
  const int t = threadIdx.x;
  const int bid = blockIdx.x;
  if (bid < 6250) {                       // h f32 -> bf16
    const size_t i = ((size_t)bid * 256 + t) * 8;
    float4 a = *(const float4*)(h + i);
    float4 b = *(const float4*)(h + i + 4);
    bf16x8 r;
    r[0] = f2us(a.x); r[1] = f2us(a.y); r[2] = f2us(a.z); r[3] = f2us(a.w);
    r[4] = f2us(b.x); r[5] = f2us(b.y); r[6] = f2us(b.z); r[7] = f2us(b.w);
    *(bf16x8*)(hb + i) = r;
  } else if (bid < 6250 + 32) {           // Wt[m][n][k] = W[m][k][n]
    const int b = bid - 6250;
    const int k0 = (b & 3) * 64, n0 = ((b >> 2) & 3) * 64;
    const float* Wm = W + (size_t)(b >> 4) * 65536;
    u16* Wtm = Wt + (size_t)(b >> 4) * 65536;
    const int lr = t >> 2, c0 = (t & 3) * 16;
#pragma unroll
    for (int i = 0; i < 16; ++i)
      tile[lr][c0 + i] = f2us(Wm[(size_t)(k0 + lr) * 256 + n0 + c0 + i]);
    __syncthreads();
#pragma unroll
    for (int i = 0; i < 16; ++i)
      Wtm[(size_t)(n0 + lr) * 256 + k0 + c0 + i] = tile[c0 + i][lr];
  } else {                                // w1t[j][k] = w1[k][j]
    const int b = bid - 6282;
    const int k0 = (b & 3) * 64, j0 = (b >> 2) * 64;
    const int lr = t >> 2, c0 = (t & 3) * 16;
#pragma unroll
    for (int i = 0; i < 16; ++i)
      tile[lr][c0 + i] = f2us(w1[(size_t)(k0 + lr) * SHID + j0 + c0 + i]);
    __syncthreads();
#pragma unroll
    for (int i = 0; i < 16; ++i)
      w1t[(size_t)(j0 + lr) * 256 + k0 + c0 + i] = tile[c0 + i][lr];
  }
}

// ---------------- CSR build (both meta-paths, replicated histogram) --------
__global__ __launch_bounds__(256) void kc_hist_both(const int* __restrict__ dst_all,
                                                    int* __restrict__ hrep) {
  int e = blockIdx.x * 256 + threadIdx.x;      // e < 2*NE
  int p = (e >= NE) ? 1 : 0;
  int rep = blockIdx.x & (NREP - 1);
  atomicAdd(hrep + ((size_t)p * NREP + rep) * (NND + 1) + dst_all[e] + 1, 1);
}

// sum replicas + block-local inclusive scan; grid = 2*NB; also zeroes wsum
__global__ __launch_bounds__(256) void ks1(const int* __restrict__ hrep,
                                           int* __restrict__ rowptr,
                                           int* __restrict__ bsum,
                                           float* __restrict__ wsum) {
  __shared__ int wsums[4];
  const int t = threadIdx.x;
  if (blockIdx.x == 0 && t < 2) wsum[t] = 0.f;
  const int p = blockIdx.x / NB, lb = blockIdx.x % NB;
  int* rp = rowptr + (size_t)p * (NND + 1);
  const int i = lb * 256 + t + 1;
  int v = 0;
  if (i <= NND) {
    const int* hp = hrep + (size_t)p * NREP * (NND + 1);
#pragma unroll
    for (int r = 0; r < NREP; ++r) v += hp[(size_t)r * (NND + 1) + i];
  }
  const int lane = t & 63, wid = t >> 6;
#pragma unroll
  for (int o = 1; o < 64; o <<= 1) {
    int u = __shfl_up(v, o, 64);
    if (lane >= o) v += u;
  }
  if (lane == 63) wsums[wid] = v;
  __syncthreads();
  if (t == 0) {
    int s = 0;
#pragma unroll
    for (int w = 0; w < 4; ++w) { int x = wsums[w]; wsums[w] = s; s += x; }
    bsum[blockIdx.x] = s;
  }
  __syncthreads();
  v += wsums[wid];
  if (i <= NND) rp[i] = v;
}

// add block-prefix + materialize single cursor per path
__global__ __launch_bounds__(256) void ks3(int* __restrict__ rowptr,
                                           const int* __restrict__ bsum,
                                           int* __restrict__ cursor) {
  __shared__ int redp[4];
  __shared__ int off_s;
  const int t = threadIdx.x;
  const int p = blockIdx.x / NB, lb = blockIdx.x % NB;
  int* rp = rowptr + (size_t)p * (NND + 1);
  int* cp = cursor + (size_t)p * NND;
  int partial = (t < lb) ? bsum[p * NB + t] : 0;
  const int lane = t & 63, wid = t >> 6;
#pragma unroll
  for (int o = 32; o; o >>= 1) partial += __shfl_xor(partial, o, 64);
  if (lane == 0) redp[wid] = partial;
  __syncthreads();
  if (t == 0) off_s = redp[0] + redp[1] + redp[2] + redp[3];
  __syncthreads();
  const int off = off_s;
  const int i = lb * 256 + t + 1;
  if (i <= NND) {
    int v = rp[i] + off;
    rp[i] = v;
    if (i < NND) cp[i] = v;
    if (i == 1) { cp[0] = 0; rp[0] = 0; }
  }
}

// scatter + per-edge attention exp for all 4 heads (CSR order)
__global__ __launch_bounds__(256) void kc_scatter(
    const int* __restrict__ src, const int* __restrict__ dst,
    int* __restrict__ cursor, int* __restrict__ col,
    const float* __restrict__ el, const float* __restrict__ er,
    float* __restrict__ exps)
{
  int e = blockIdx.x * 256 + threadIdx.x;
  if (e >= NE) return;
  int s = src[e], d = dst[e];
  int pos = atomicAdd(cursor + d, 1);
  col[pos] = s;
  float4 a = *(const float4*)(el + s * 4);
  float4 b = *(const float4*)(er + d * 4);
  float4 r;
  float x;
  x = a.x + b.x; x = x > 0.f ? x : SLOPE * x; r.x = __expf(x);
  x = a.y + b.y; x = x > 0.f ? x : SLOPE * x; r.y = __expf(x);
  x = a.z + b.z; x = x > 0.f ? x : SLOPE * x; r.z = __expf(x);
  x = a.w + b.w; x = x > 0.f ? x : SLOPE * x; r.w = __expf(x);
  *(float4*)(exps + (size_t)pos * 4) = r;
}

// ---------------- K1: feat = h @ W[m], 128x256 tile, 8 waves, fused el/er --
// Wave (wr,wc): rows row0+wr*64.. x cols wc*64.. ; head = wc.
__global__ __launch_bounds__(512) void k1_mfma(
    const u16* __restrict__ hb, const u16* __restrict__ Wt,
    const float* __restrict__ al, const float* __restrict__ ar,
    u16* __restrict__ feat, float* __restrict__ el, float* __restrict__ er)
{
  __shared__ u16 As[128 * 64];    // 16 KB
  __shared__ u16 Bs[256 * 64];    // 32 KB
  const int t = threadIdx.x;
  const int lane = t & 63;
  const int w = t >> 6;           // 0..7
  const int wr = w >> 2, wc = w & 3;
  const int row0 = blockIdx.x * 128;

  const int srow = t >> 3;              // 0..63
  const int sg   = t & 7;
  const int sgl  = (sg ^ (srow & 7)) * 8;  // swizzled source col offset

  int ra[2], cb[4];
#pragma unroll
  for (int q = 0; q < 2; ++q) {
    int r = row0 + q * 64 + srow; if (r >= NND) r = NND - 1;
    ra[q] = r;
  }
#pragma unroll
  for (int q = 0; q < 4; ++q) cb[q] = q * 64 + srow;

  f32x4 acc[4][4];
#pragma unroll
  for (int i = 0; i < 4; ++i)
#pragma unroll
    for (int j = 0; j < 4; ++j) acc[i][j] = (f32x4){0.f, 0.f, 0.f, 0.f};

  for (int ks = 0; ks < 4; ++ks) {
    const int kb = ks * 64 + sgl;
    __syncthreads();
#pragma unroll
    for (int q = 0; q < 2; ++q)
      GLDS(hb + (size_t)ra[q] * INF + kb, As + q * 4096 + w * 512);
#pragma unroll
    for (int q = 0; q < 4; ++q)
      GLDS(Wt + (size_t)cb[q] * 256 + kb, Bs + q * 4096 + w * 512);
    __syncthreads();
#pragma unroll
    for (int kk = 0; kk < 2; ++kk) {
      bf16x8 af[4], bfr[4];
#pragma unroll
      for (int mi = 0; mi < 4; ++mi) {
        const int R = wr * 64 + mi * 16 + (lane & 15);
        const int g = kk * 4 + (lane >> 4);
        af[mi] = *(const bf16x8*)(As + R * 64 + (g ^ (R & 7)) * 8);
      }
#pragma unroll
      for (int ni = 0; ni < 4; ++ni) {
        const int R = wc * 64 + ni * 16 + (lane & 15);
        const int g = kk * 4 + (lane >> 4);
        bfr[ni] = *(const bf16x8*)(Bs + R * 64 + (g ^ (R & 7)) * 8);
      }
#pragma unroll
      for (int mi = 0; mi < 4; ++mi)
#pragma unroll
        for (int ni = 0; ni < 4; ++ni)
          acc[mi][ni] = __builtin_amdgcn_mfma_f32_16x16x32_bf16(af[mi], bfr[ni], acc[mi][ni], 0, 0, 0);
    }
  }
  // epilogue: feat store + fused el/er (C layout col=lane&15, row=(lane>>4)*4+i)
  const int head = wc;
  float alc[4], arc[4];
#pragma unroll
  for (int ni = 0; ni < 4; ++ni) {
    const int c = wc * 64 + ni * 16 + (lane & 15);
    alc[ni] = al[c]; arc[ni] = ar[c];
  }
#pragma unroll
  for (int mi = 0; mi < 4; ++mi) {
#pragma unroll
    for (int i = 0; i < 4; ++i) {
      const int r = row0 + wr * 64 + mi * 16 + (lane >> 4) * 4 + i;
      const bool valid = (r < NND);
      float pel = 0.f, per = 0.f;
#pragma unroll
      for (int ni = 0; ni < 4; ++ni) {
        const float fe = acc[mi][ni][i];
        if (valid)
          feat[(size_t)r * HDIM + wc * 64 + ni * 16 + (lane & 15)] = f2us(fe);
        pel = fmaf(fe, alc[ni], pel);
        per = fmaf(fe, arc[ni], per);
      }
#pragma unroll
      for (int o = 1; o < 16; o <<= 1) {
        pel += __shfl_xor(pel, o, 64);
        per += __shfl_xor(per, o, 64);
      }
      if (valid && (lane & 15) == 0) {
        el[r * 4 + head] = pel;
        er[r * 4 + head] = per;
      }
    }
  }
}

// ---------------- K3: CSR gather (round-7 form, unchanged) -----------------
template<int OBF>
__global__ __launch_bounds__(256) void k3_gather(
    const int* __restrict__ rowptr, const int* __restrict__ col,
    const float* __restrict__ exps,
    const u16* __restrict__ feat, void* __restrict__ z)
{
  const int d = blockIdx.x * 4 + (threadIdx.x >> 6);
  if (d >= NND) return;
  const int lane = threadIdx.x & 63;
  const int h = lane >> 4;
  const int sub = lane & 15;
  const int beg = rowptr[d], end = rowptr[d + 1];

  float den = 0.f;
  for (int j = beg + sub; j < end; j += 16)
    den += exps[(size_t)j * 4 + h];
#pragma unroll
  for (int o = 1; o < 16; o <<= 1) den += __shfl_xor(den, o, 64);
  const float inv = 1.f / fmaxf(den, 1e-9f);

  float a0 = 0.f, a1 = 0.f, a2 = 0.f, a3 = 0.f;
  int j = beg;
  for (; j + 3 < end; j += 4) {
    int s0 = col[j], s1 = col[j + 1], s2 = col[j + 2], s3 = col[j + 3];
    float p0 = exps[(size_t)j * 4 + h] * inv;
    float p1 = exps[(size_t)(j + 1) * 4 + h] * inv;
    float p2 = exps[(size_t)(j + 2) * 4 + h] * inv;
    float p3 = exps[(size_t)(j + 3) * 4 + h] * inv;
    const ushort4 f0 = *(const ushort4*)(feat + (size_t)s0 * HDIM + lane * 4);
    const ushort4 f1 = *(const ushort4*)(feat + (size_t)s1 * HDIM + lane * 4);
    const ushort4 f2 = *(const ushort4*)(feat + (size_t)s2 * HDIM + lane * 4);
    const ushort4 f3 = *(const ushort4*)(feat + (size_t)s3 * HDIM + lane * 4);
    a0 = fmaf(p0, us2f(f0.x), a0); a1 = fmaf(p0, us2f(f0.y), a1);
    a2 = fmaf(p0, us2f(f0.z), a2); a3 = fmaf(p0, us2f(f0.w), a3);
    a0 = fmaf(p1, us2f(f1.x), a0); a1 = fmaf(p1, us2f(f1.y), a1);
    a2 = fmaf(p1, us2f(f1.z), a2); a3 = fmaf(p1, us2f(f1.w), a3);
    a0 = fmaf(p2, us2f(f2.x), a0); a1 = fmaf(p2, us2f(f2.y), a1);
    a2 = fmaf(p2, us2f(f2.z), a2); a3 = fmaf(p2, us2f(f2.w), a3);
    a0 = fmaf(p3, us2f(f3.x), a0); a1 = fmaf(p3, us2f(f3.y), a1);
    a2 = fmaf(p3, us2f(f3.z), a2); a3 = fmaf(p3, us2f(f3.w), a3);
  }
  for (; j < end; ++j) {
    int s = col[j];
    float p = exps[(size_t)j * 4 + h] * inv;
    const ushort4 f4 = *(const ushort4*)(feat + (size_t)s * HDIM + lane * 4);
    a0 = fmaf(p, us2f(f4.x), a0); a1 = fmaf(p, us2f(f4.y), a1);
    a2 = fmaf(p, us2f(f4.z), a2); a3 = fmaf(p, us2f(f4.w), a3);
  }
  a0 = a0 > 0.f ? a0 : expf(a0) - 1.f;
  a1 = a1 > 0.f ? a1 : expf(a1) - 1.f;
  a2 = a2 > 0.f ? a2 : expf(a2) - 1.f;
  a3 = a3 > 0.f ? a3 : expf(a3) - 1.f;
  const size_t idx = (size_t)d * HDIM + lane * 4;
  if (OBF) {
    ushort4 r; r.x = f2us(a0); r.y = f2us(a1); r.z = f2us(a2); r.w = f2us(a3);
    *(ushort4*)((u16*)z + idx) = r;
  } else {
    float4 r; r.x = a0; r.y = a1; r.z = a2; r.w = a3;
    *(float4*)((float*)z + idx) = r;
  }
}

// ---------------- K4: wsum[m] += sum tanh(z@w1+b1)*w2, 256x128, 8 waves ----
template<int ZBF>
__global__ __launch_bounds__(512) void k4_mfma(
    const void* __restrict__ zsrc, const u16* __restrict__ w1t,
    const float* __restrict__ b1, const float* __restrict__ w2,
    float* __restrict__ wsum, int midx)
{
  __shared__ u16 As[256 * 64];    // 32 KB
  __shared__ u16 Bs[128 * 64];    // 16 KB
  __shared__ float red[8];
  const int t = threadIdx.x;
  const int lane = t & 63;
  const int w = t >> 6;           // 0..7
  const int wr = w >> 1, wc = w & 1;
  const int row0 = blockIdx.x * 256;
  const int srow = t >> 3;        // 0..63
  const int sg   = t & 7;
  const int sgl  = (sg ^ (srow & 7)) * 8;

  int ra[4], cb[2];
#pragma unroll
  for (int q = 0; q < 4; ++q) {
    int r = row0 + q * 64 + srow; if (r >= NND) r = NND - 1;
    ra[q] = r;
  }
#pragma unroll
  for (int q = 0; q < 2; ++q) cb[q] = q * 64 + srow;   // w1t rows 0..127

  f32x4 acc[4][4];
#pragma unroll
  for (int i = 0; i < 4; ++i)
#pragma unroll
    for (int j = 0; j < 4; ++j) acc[i][j] = (f32x4){0.f, 0.f, 0.f, 0.f};

  for (int ks = 0; ks < 4; ++ks) {
    const int kb = ks * 64 + sgl;
    __syncthreads();
    if (ZBF) {
#pragma unroll
      for (int q = 0; q < 4; ++q)
        GLDS((const u16*)zsrc + (size_t)ra[q] * HDIM + kb, As + q * 4096 + w * 512);
    } else {
      const float* zf = (const float*)zsrc;
#pragma unroll
      for (int q = 0; q < 4; ++q) {
        float4 a = *(const float4*)(zf + (size_t)ra[q] * HDIM + kb);
        float4 b = *(const float4*)(zf + (size_t)ra[q] * HDIM + kb + 4);
        bf16x8 r;
        r[0] = f2us(a.x); r[1] = f2us(a.y); r[2] = f2us(a.z); r[3] = f2us(a.w);
        r[4] = f2us(b.x); r[5] = f2us(b.y); r[6] = f2us(b.z); r[7] = f2us(b.w);
        *(bf16x8*)(As + (q * 64 + srow) * 64 + (sg ^ (srow & 7)) * 8) = r;
      }
    }
#pragma unroll
    for (int q = 0; q < 2; ++q)
      GLDS(w1t + (size_t)cb[q] * 256 + kb, Bs + q * 4096 + w * 512);
    __syncthreads();
#pragma unroll
    for (int kk = 0; kk < 2; ++kk) {
      bf16x8 af[4], bfr[4];
#pragma unroll
      for (int mi = 0; mi < 4; ++mi) {
        const int R = wr * 64 + mi * 16 + (lane & 15);
        const int g = kk * 4 + (lane >> 4);
        af[mi] = *(const bf16x8*)(As + R * 64 + (g ^ (R & 7)) * 8);
      }
#pragma unroll
      for (int ni = 0; ni < 4; ++ni) {
        const int R = wc * 64 + ni * 16 + (lane & 15);
        const int g = kk * 4 + (lane >> 4);
        bfr[ni] = *(const bf16x8*)(Bs + R * 64 + (g ^ (R & 7)) * 8);
      }
#pragma unroll
      for (int mi = 0; mi < 4; ++mi)
#pragma unroll
        for (int ni = 0; ni < 4; ++ni)
          acc[mi][ni] = __builtin_amdgcn_mfma_f32_16x16x32_bf16(af[mi], bfr[ni], acc[mi][ni], 0, 0, 0);
    }
  }
  float sum = 0.f;
#pragma unroll
  for (int ni = 0; ni < 4; ++ni) {
    const int c = wc * 64 + ni * 16 + (lane & 15);
    const float b1c = b1[c], w2c = w2[c];
#pragma unroll
    for (int mi = 0; mi < 4; ++mi) {
      const int r_base = row0 + wr * 64 + mi * 16 + (lane >> 4) * 4;
#pragma unroll
      for (int i = 0; i < 4; ++i) {
        if (r_base + i < NND)
          sum += tanhf(acc[mi][ni][i] + b1c) * w2c;
      }
    }
  }
#pragma unroll
  for (int o = 32; o; o >>= 1) sum += __shfl_xor(sum, o, 64);
  if (lane == 0) red[w] = sum;
  __syncthreads();
  if (t == 0) {
    float s = 0.f;
#pragma unroll
    for (int q = 0; q < 8; ++q) s += red[q];
    unsafeAtomicAdd(wsum + midx, s);
  }
}

// ---------------- K5: beta=softmax(wsum/N); out = b0*z0 + b1*z1 ------------
__global__ __launch_bounds__(256) void k5_out(
    float* __restrict__ out, const u16* __restrict__ z1,
    const float* __restrict__ wsum)
{
  const int i = blockIdx.x * 256 + threadIdx.x;
  float w0 = wsum[0] * (1.0f / NND);
  float w1v = wsum[1] * (1.0f / NND);
  float mx = fmaxf(w0, w1v);
  float e0 = expf(w0 - mx), e1 = expf(w1v - mx);
  float inv = 1.f / (e0 + e1);
  float b0 = e0 * inv, b1 = e1 * inv;
  float4 a = ((const float4*)out)[i];
  ushort4 zb = ((const ushort4*)z1)[i];
  float4 r;
  r.x = b0 * a.x + b1 * us2f(zb.x);
  r.y = b0 * a.y + b1 * us2f(zb.y);
  r.z = b0 * a.z + b1 * us2f(zb.z);
  r.w = b0 * a.w + b1 * us2f(zb.w);
  ((float4*)out)[i] = r;
}

extern "C" void kernel_launch(void* const* d_in, const int* in_sizes, int n_in,
                              void* d_out, int out_size, void* d_ws, size_t ws_size,
                              hipStream_t stream)
{
  const float* h  = (const float*)d_in[0];
  const int* src  = (const int*)d_in[1];
  const int* dst  = (const int*)d_in[2];
  const float* W  = (const float*)d_in[3];
  const float* al = (const float*)d_in[4];
  const float* ar = (const float*)d_in[5];
  const float* w1 = (const float*)d_in[6];
  const float* b1 = (const float*)d_in[7];
  const float* w2 = (const float*)d_in[8];

  // workspace layout (bytes)
  char* wsb = (char*)d_ws;
  u16*   feat   = (u16*)(wsb);                 // 25,600,000
  u16*   hz     = (u16*)(wsb + 25600000);      // 25,600,000  (bf16 h; z1 aliases)
  float* exps   = (float*)(wsb + 51200000);    // 12,800,000
  int*   col    = (int*)(wsb + 64000000);      //  3,200,000
  u16*   Wt     = (u16*)(wsb + 67200000);      //    262,144
  u16*   w1t    = (u16*)(wsb + 67462144);      //     65,536
  float* el     = (float*)(wsb + 67527680);    //    800,000
  float* er     = (float*)(wsb + 68327680);    //    800,000
  int*   rowptr = (int*)(wsb + 69127680);      //    400,008 (2 paths)
  int*   cursor = (int*)(wsb + 69527688);      //    400,000 (2 paths)
  float* wsum   = (float*)(wsb + 69927688);    //          8
  int*   bsum   = (int*)(wsb + 69927696);      //      1,568 (2*NB)
  int*   hrep   = (int*)(wsb + 69929264);      //  6,400,128 (2*NREP*(NND+1))
  const size_t NEED = 76329392;
  if (ws_size < NEED) {
    hipMemsetAsync(d_out, 0x7F, (size_t)out_size * 4, stream);
    return;
  }
  u16* z1 = hz;        // alias: hz dead after k1_mfma(m=1), z1 written by k3(m=1)
  float* outp = (float*)d_out;

  // phase A: prep + full CSR build for both paths
  kprep<<<6290, 256, 0, stream>>>(h, hz, W, Wt, w1, w1t);
  hipMemsetAsync(hrep, 0, (size_t)2 * NREP * (NND + 1) * sizeof(int), stream);
  kc_hist_both<<<2 * NE / 256, 256, 0, stream>>>(dst, hrep);
  ks1<<<2 * NB, 256, 0, stream>>>(hrep, rowptr, bsum, wsum);
  ks3<<<2 * NB, 256, 0, stream>>>(rowptr, bsum, cursor);

  // phase B: per meta-path
  for (int m = 0; m < NM; ++m) {
    const int* src_m = src + (size_t)m * NE;
    const int* dst_m = dst + (size_t)m * NE;
    int* rowptr_m = rowptr + (size_t)m * (NND + 1);
    int* cursor_m = cursor + (size_t)m * NND;
    k1_mfma<<<391, 512, 0, stream>>>(hz, Wt + (size_t)m * 65536,
                                     al + (size_t)m * HDIM, ar + (size_t)m * HDIM,
                                     feat, el, er);
    kc_scatter<<<NE / 256, 256, 0, stream>>>(src_m, dst_m, cursor_m, col, el, er, exps);
    if (m == 0) {
      k3_gather<0><<<12500, 256, 0, stream>>>(rowptr_m, col, exps, feat, d_out);
      k4_mfma<0><<<196, 512, 0, stream>>>(d_out, w1t, b1, w2, wsum, 0);
    } else {
      k3_gather<1><<<12500, 256, 0, stream>>>(rowptr_m, col, exps, feat, z1);
      k4_mfma<1><<<196, 512, 0, stream>>>(z1, w1t, b1, w2, wsum, 1);
    }
  }
  k5_out<<<(NND * HDIM / 4) / 256, 256, 0, stream>>>(outp, z1, wsum);
}